// Round 4
// baseline (4257.150 us; speedup 1.0000x reference)
//
#include <hip/hip_runtime.h>
#include <hip/hip_bf16.h>

static constexpr int LL = 256;   // sequence length / nodes
static constexpr int BB = 128;   // batch
static constexpr int HHH = 512;  // hidden dim

typedef __attribute__((ext_vector_type(8))) short bf16x8;
typedef __attribute__((ext_vector_type(4))) float f32x4;
typedef __attribute__((ext_vector_type(8))) unsigned short u16x8;
typedef __attribute__((ext_vector_type(4))) unsigned short u16x4;

__device__ __forceinline__ unsigned short f2bf(float f) {
  union { float f; unsigned u; } v; v.f = f;
  unsigned r = (v.u + 0x7FFFu + ((v.u >> 16) & 1u)) >> 16;
  return (unsigned short)r;
}
__device__ __forceinline__ float bf2f(unsigned short s) {
  union { unsigned u; float f; } v; v.u = ((unsigned)s) << 16;
  return v.f;
}
__device__ __forceinline__ float sigm(float x) { return 1.0f / (1.0f + __expf(-x)); }
__device__ __forceinline__ float tanh_f(float x) { return 1.0f - 2.0f / (__expf(2.0f * x) + 1.0f); }

// ---------------------------------------------------------------------------
// Kernel 0: zero the per-node completion flags + ticket counters (every call).
// ---------------------------------------------------------------------------
__global__ __launch_bounds__(256) void zero_flags(int* __restrict__ flag,
                                                  int* __restrict__ tick) {
  int i = blockIdx.x * 256 + threadIdx.x;
  if (i < LL * BB) flag[i] = 0;
  if (i < 16) tick[i] = 0;
}

// ---------------------------------------------------------------------------
// Kernel 1a: cast the 4 x-weight matrices to bf16 (row-major, K-major rows).
// ---------------------------------------------------------------------------
__global__ __launch_bounds__(256) void wcast4(
    const float* __restrict__ s0, const float* __restrict__ s1,
    const float* __restrict__ s2, const float* __restrict__ s3,
    unsigned short* __restrict__ wx) {
  int gid = blockIdx.x * 256 + threadIdx.x;
  int e = gid * 4;
  int m = e >> 18;            // which of 4 matrices (512*512 elems each)
  int off = e & 0x3FFFF;
  const float* srcs[4] = {s0, s1, s2, s3};
  float4 v = *(const float4*)(srcs[m] + off);
  u16x4 o;
  o[0] = f2bf(v.x); o[1] = f2bf(v.y); o[2] = f2bf(v.z); o[3] = f2bf(v.w);
  *(u16x4*)(wx + (size_t)m * 262144 + off) = o;
}

// ---------------------------------------------------------------------------
// Kernel 1b: pack the 4 h-weight matrices into MFMA B-fragment order (bf16).
// Whp block id = (g*32 + n16)*16 + kb, each block = 64 lanes * 8 bf16 = 1KB;
// lane l holds W[g][n16*16 + (l&15)][kb*32 + (l>>4)*8 + 0..7].
// ---------------------------------------------------------------------------
__global__ __launch_bounds__(256) void whpack(
    const float* __restrict__ Wi_h, const float* __restrict__ Wf_h,
    const float* __restrict__ Wo_h, const float* __restrict__ Wu_h,
    unsigned short* __restrict__ Whp) {
  int gid = blockIdx.x * 256 + threadIdx.x;   // 131072 threads total
  int lane = gid & 63;
  int kb   = (gid >> 6) & 15;
  int n16  = (gid >> 10) & 31;
  int g    = gid >> 15;
  const float* W = (g == 0) ? Wi_h : (g == 1) ? Wf_h : (g == 2) ? Wo_h : Wu_h;
  int row = n16 * 16 + (lane & 15);
  int col = kb * 32 + (lane >> 4) * 8;
  const float4* s = (const float4*)(W + (size_t)row * 512 + col);
  float4 v0 = s[0], v1 = s[1];
  u16x8 o;
  o[0] = f2bf(v0.x); o[1] = f2bf(v0.y); o[2] = f2bf(v0.z); o[3] = f2bf(v0.w);
  o[4] = f2bf(v1.x); o[5] = f2bf(v1.y); o[6] = f2bf(v1.z); o[7] = f2bf(v1.w);
  *(u16x8*)&Whp[(size_t)gid * 8] = o;
}

// ---------------------------------------------------------------------------
// Kernel 2: level assignment + bucketing + tile-list emission.
// One block, 128 threads (one per batch column).
// pairs: node ids (t*128+b) grouped by level (topological order).
// mrows[i] = (rbase << 6) | rcnt for each 32-row tile, in level order.
// lmeta[0] = number of tiles (mcnt).
// ---------------------------------------------------------------------------
__global__ __launch_bounds__(128) void levels_k(
    const int* __restrict__ parents, int* __restrict__ pairs,
    int* __restrict__ lmeta, int* __restrict__ mrows) {
  __shared__ unsigned short cnt2[128][130];  // per (b, level) counts -> starts
  __shared__ int off[130];
  __shared__ int maxl_sh;
  const int b = threadIdx.x;
  unsigned char mylvl[256];                  // private per-column levels
  for (int l = 0; l < 130; ++l) cnt2[b][l] = 0;
  if (b == 0) maxl_sh = 0;
  __syncthreads();
  int maxl = 0;
  for (int t = 0; t < 256; ++t) {
    int p = parents[t * 128 + b];
    int l = (p < 0) ? 0 : (mylvl[p] + 1);
    if (l > 127) l = 127;                    // safety clamp
    mylvl[t] = (unsigned char)l;
    maxl = l > maxl ? l : maxl;
    cnt2[b][l]++;
  }
  atomicMax(&maxl_sh, maxl);
  __syncthreads();
  const int nlev = maxl_sh + 1;
  {
    int l = b;
    int s = 0;
    if (l < nlev) for (int bb = 0; bb < 128; ++bb) s += cnt2[bb][l];
    off[l + 1] = s;
  }
  __syncthreads();
  if (b == 0) {
    off[0] = 0;
    for (int l = 0; l < 128; ++l) off[l + 1] += off[l];
  }
  __syncthreads();
  {
    int l = b;
    if (l < nlev) {
      int run = off[l];
      for (int bb = 0; bb < 128; ++bb) {
        int c = cnt2[bb][l];
        cnt2[bb][l] = (unsigned short)run;
        run += c;
      }
    }
  }
  __syncthreads();
  for (int t = 0; t < 256; ++t) {
    int l = mylvl[t];
    int pos = cnt2[b][l]++;
    pairs[pos] = t * 128 + b;
  }
  if (b == 0) {
    int midx = 0;
    for (int l = 0; l < nlev; ++l) {
      int s = off[l], e = off[l + 1];
      for (int rb = s; rb < e; rb += 32) {
        int rc = (e - rb < 32) ? (e - rb) : 32;
        mrows[midx++] = (rb << 6) | rc;
      }
    }
    lmeta[0] = midx;
  }
}

// ---------------------------------------------------------------------------
// Kernel 3: Xpre[t*B+b][g*512+h] = x[t,b,:] . Wg_x[h,:] + bias_g[h]   (bf16)
// GEMM M=32768 N=2048 K=512.  64x64 tile, BK=64, 4 waves.
// ---------------------------------------------------------------------------
__global__ __launch_bounds__(256) void xproj(
    const float* __restrict__ X, const unsigned short* __restrict__ Wx,
    const float* __restrict__ bi_x, const float* __restrict__ bi_h,
    const float* __restrict__ bf_x, const float* __restrict__ bf_h,
    unsigned short* __restrict__ Xpre) {
  __shared__ unsigned short As[64][72];
  __shared__ unsigned short Bs[64][72];
  const int m0 = blockIdx.x * 64;
  const int n0 = blockIdx.y * 64;
  const int tid = threadIdx.x;
  const int r = tid >> 2, c4 = tid & 3;
  const int lane = tid & 63, w = tid >> 6;
  f32x4 acc[4] = {};
  for (int kt = 0; kt < 8; ++kt) {
    const int k0 = kt * 64;
    __syncthreads();
    {
      const float* src = X + (size_t)(m0 + r) * 512 + k0 + c4 * 16;
      float4 v0 = ((const float4*)src)[0];
      float4 v1 = ((const float4*)src)[1];
      float4 v2 = ((const float4*)src)[2];
      float4 v3 = ((const float4*)src)[3];
      u16x8 p0, p1;
      p0[0] = f2bf(v0.x); p0[1] = f2bf(v0.y); p0[2] = f2bf(v0.z); p0[3] = f2bf(v0.w);
      p0[4] = f2bf(v1.x); p0[5] = f2bf(v1.y); p0[6] = f2bf(v1.z); p0[7] = f2bf(v1.w);
      p1[0] = f2bf(v2.x); p1[1] = f2bf(v2.y); p1[2] = f2bf(v2.z); p1[3] = f2bf(v2.w);
      p1[4] = f2bf(v3.x); p1[5] = f2bf(v3.y); p1[6] = f2bf(v3.z); p1[7] = f2bf(v3.w);
      *(u16x8*)&As[r][c4 * 16] = p0;
      *(u16x8*)&As[r][c4 * 16 + 8] = p1;
      const unsigned short* sb = Wx + (size_t)(n0 + r) * 512 + k0 + c4 * 16;
      u16x8 q0 = ((const u16x8*)sb)[0];
      u16x8 q1 = ((const u16x8*)sb)[1];
      *(u16x8*)&Bs[r][c4 * 16] = q0;
      *(u16x8*)&Bs[r][c4 * 16 + 8] = q1;
    }
    __syncthreads();
#pragma unroll
    for (int kk = 0; kk < 64; kk += 32) {
      const int ko = kk + 8 * (lane >> 4);
      bf16x8 af = *(const bf16x8*)&As[w * 16 + (lane & 15)][ko];
#pragma unroll
      for (int n = 0; n < 4; ++n) {
        bf16x8 bfr = *(const bf16x8*)&Bs[n * 16 + (lane & 15)][ko];
        acc[n] = __builtin_amdgcn_mfma_f32_16x16x32_bf16(af, bfr, acc[n], 0, 0, 0);
      }
    }
  }
#pragma unroll
  for (int n = 0; n < 4; ++n) {
    const int gcol = n0 + n * 16 + (lane & 15);
    const int g = gcol >> 9, hh = gcol & 511;
    float badd = 0.0f;
    if (g == 0) badd = bi_x[hh] + bi_h[hh];
    else if (g == 1) badd = bf_x[hh] + bf_h[hh];
    const int rbase = m0 + w * 16 + (lane >> 4) * 4;
#pragma unroll
    for (int q = 0; q < 4; ++q) {
      Xpre[(size_t)(rbase + q) * 2048 + gcol] = f2bf(acc[n][q] + badd);
    }
  }
}

// ---------------------------------------------------------------------------
// Kernel 4: recurrence via per-node readiness flags + per-ct ticket queues.
// NO grid.sync, NO cooperative launch.  Deadlock-free at any occupancy:
// a WG only waits on strictly earlier tickets (parents are earlier levels).
// WG ct = blockIdx&15 owns cols [ct*32, ct*32+32) of all 4 gates; its wave w
// holds gate w's weight fragments for those cols in 128 VGPRs (stationary).
// flag[node] counts completed col-tiles; ready when == 16.
// ---------------------------------------------------------------------------
__global__ __launch_bounds__(256, 2) void treelstm_flag(
    const unsigned short* __restrict__ Xpre,  // [L*B][2048]
    const unsigned short* __restrict__ Whp,   // packed [4][32][16][512]
    const int* __restrict__ parents,          // [L][B]
    const int* __restrict__ pairs,            // [32768] node ids by level
    const int* __restrict__ lmeta,            // [0] = mcnt
    const int* __restrict__ mrows,            // tile list (rbase<<6 | rcnt)
    int* __restrict__ flag,                   // [32768] completion counters
    int* __restrict__ tick,                   // [16] ticket counters
    float* __restrict__ Hout,                 // [B][L][H]  (d_out)
    float* __restrict__ Cbuf,                 // [B][L][H]
    unsigned short* __restrict__ Hbf) {       // [B][L][H] bf16
  __shared__ unsigned short phs[32][536];     // 34.3KB (round-2 proven layout)
  __shared__ float gbuf[4][32][33];           // 16.9KB
  __shared__ int sh_ticket;
  const int tid = threadIdx.x;
  const int lane = tid & 63, w = tid >> 6;
  const int ct = blockIdx.x & 15;
  const int c0 = ct * 32;
  const int mcnt = lmeta[0];

  // ---- preload weights for (gate w, cols c0..c0+31) into registers ----
  bf16x8 wfrag[2][16];
  {
    const size_t base = (size_t)((w * 32 + ct * 2) * 16) * 512 + lane * 8;
#pragma unroll
    for (int kb = 0; kb < 16; ++kb) {
      wfrag[0][kb] = *(const bf16x8*)&Whp[base + (size_t)kb * 512];
      wfrag[1][kb] = *(const bf16x8*)&Whp[base + (size_t)(16 + kb) * 512];
    }
  }

  while (true) {
    __syncthreads();   // protect sh_ticket / phs / gbuf from previous iter
    if (tid == 0) sh_ticket = atomicAdd(&tick[ct], 1);
    __syncthreads();
    const int my = sh_ticket;
    if (my >= mcnt) break;
    const int mr = mrows[my];
    const int rbase = mr >> 6;
    const int rcnt = mr & 63;

    // thread -> (row r = tid>>3, chunk q = tid&7)
    const int r = tid >> 3;
    const int q = tid & 7;
    int node = 0, p = -1, b = 0;
    if (r < rcnt) {
      node = pairs[rbase + r];
      p = parents[node];
      b = node & 127;
    }
    // wait for parent completion (all 16 col-tiles), then gather its h row
    if (p >= 0) {
      const int pn = p * 128 + b;
      while (__hip_atomic_load(&flag[pn], __ATOMIC_ACQUIRE,
                               __HIP_MEMORY_SCOPE_AGENT) < 16)
        __builtin_amdgcn_s_sleep(2);
      const unsigned short* src = Hbf + ((size_t)b * LL + p) * HHH + q * 64;
#pragma unroll
      for (int j = 0; j < 8; ++j)
        *(u16x8*)&phs[r][q * 64 + j * 8] = ((const u16x8*)src)[j];
    } else {
      u16x8 z = {};
#pragma unroll
      for (int j = 0; j < 8; ++j) *(u16x8*)&phs[r][q * 64 + j * 8] = z;
    }
    __syncthreads();

    // wave w: gate w, 32 rows x 32 cols, K = 512 (weights in registers)
    f32x4 acc[2][2] = {};
    const int hi = lane >> 4;
#pragma unroll
    for (int kb = 0; kb < 16; ++kb) {
      const int ko = kb * 32 + 8 * hi;
      bf16x8 a0 = *(const bf16x8*)&phs[lane & 15][ko];
      bf16x8 a1 = *(const bf16x8*)&phs[16 + (lane & 15)][ko];
      acc[0][0] = __builtin_amdgcn_mfma_f32_16x16x32_bf16(a0, wfrag[0][kb], acc[0][0], 0, 0, 0);
      acc[1][0] = __builtin_amdgcn_mfma_f32_16x16x32_bf16(a1, wfrag[0][kb], acc[1][0], 0, 0, 0);
      acc[0][1] = __builtin_amdgcn_mfma_f32_16x16x32_bf16(a0, wfrag[1][kb], acc[0][1], 0, 0, 0);
      acc[1][1] = __builtin_amdgcn_mfma_f32_16x16x32_bf16(a1, wfrag[1][kb], acc[1][1], 0, 0, 0);
    }
#pragma unroll
    for (int mi = 0; mi < 2; ++mi)
#pragma unroll
      for (int ni = 0; ni < 2; ++ni)
#pragma unroll
        for (int qq = 0; qq < 4; ++qq)
          gbuf[w][mi * 16 + (lane >> 4) * 4 + qq][ni * 16 + (lane & 15)] = acc[mi][ni][qq];
    __syncthreads();

    // elementwise gates: same thread -> (row r, 4 hidden cols q*4)
    if (r < rcnt) {
      const int hc = q * 4;
      const int t = node >> 7;
      const int h = c0 + hc;
      float4 pc = make_float4(0.f, 0.f, 0.f, 0.f);
      if (p >= 0) pc = *(const float4*)(Cbuf + ((size_t)b * LL + p) * HHH + h);
      float xg[4][4];
#pragma unroll
      for (int g = 0; g < 4; ++g) {
        u16x4 xv = *(const u16x4*)(Xpre + (size_t)node * 2048 + g * 512 + h);
#pragma unroll
        for (int j = 0; j < 4; ++j) xg[g][j] = bf2f(xv[j]);
      }
      const float pcv[4] = {pc.x, pc.y, pc.z, pc.w};
      float cva[4], hva[4];
#pragma unroll
      for (int j = 0; j < 4; ++j) {
        float iv = sigm(gbuf[0][r][hc + j] + xg[0][j]);
        float fv = sigm(gbuf[1][r][hc + j] + xg[1][j]);
        float ov = sigm(gbuf[2][r][hc + j] + xg[2][j]);
        float uv = tanh_f(gbuf[3][r][hc + j] + xg[3][j]);
        float cv = iv * uv + fv * pcv[j];
        cva[j] = cv;
        hva[j] = ov * tanh_f(cv);
      }
      const size_t obase = ((size_t)b * LL + t) * HHH + h;
      *(float4*)(Cbuf + obase) = make_float4(cva[0], cva[1], cva[2], cva[3]);
      *(float4*)(Hout + obase) = make_float4(hva[0], hva[1], hva[2], hva[3]);
      u16x4 hb;
      hb[0] = f2bf(hva[0]); hb[1] = f2bf(hva[1]);
      hb[2] = f2bf(hva[2]); hb[3] = f2bf(hva[3]);
      *(u16x4*)(Hbf + obase) = hb;
    }
    __threadfence();
    // one completion increment per row of this col-tile
    if (r < rcnt && q == 0)
      __hip_atomic_fetch_add(&flag[node], 1, __ATOMIC_RELEASE,
                             __HIP_MEMORY_SCOPE_AGENT);
  }
}

// ---------------------------------------------------------------------------
extern "C" void kernel_launch(void* const* d_in, const int* in_sizes, int n_in,
                              void* d_out, int out_size, void* d_ws, size_t ws_size,
                              hipStream_t stream) {
  const float* X    = (const float*)d_in[0];
  const float* Wi_x = (const float*)d_in[1];
  const float* bi_x = (const float*)d_in[2];
  const float* Wi_h = (const float*)d_in[3];
  const float* bi_h = (const float*)d_in[4];
  const float* Wf_x = (const float*)d_in[5];
  const float* bf_x = (const float*)d_in[6];
  const float* Wf_h = (const float*)d_in[7];
  const float* bf_h = (const float*)d_in[8];
  const float* Wo_x = (const float*)d_in[9];
  const float* Wo_h = (const float*)d_in[10];
  const float* Wu_x = (const float*)d_in[11];
  const float* Wu_h = (const float*)d_in[12];
  const int* parents = (const int*)d_in[13];
  float* Hout = (float*)d_out;

  char* ws = (char*)d_ws;
  unsigned short* Xpre = (unsigned short*)ws; ws += (size_t)32768 * 2048 * 2;  // 128 MB
  unsigned short* Hbf  = (unsigned short*)ws; ws += (size_t)BB * LL * HHH * 2; // 32 MB
  float*          Cbuf = (float*)ws;          ws += (size_t)BB * LL * HHH * 4; // 64 MB
  unsigned short* Wxbf = (unsigned short*)ws; ws += (size_t)2048 * 512 * 2;    // 2 MB
  unsigned short* Whp  = (unsigned short*)ws; ws += (size_t)2048 * 512 * 2;    // 2 MB
  int*            pairs = (int*)ws;           ws += (size_t)32768 * 4;         // 128 KB
  int*            lmeta = (int*)ws;           ws += 256 * 4;
  int*            mrows = (int*)ws;           ws += 4096 * 4;
  int*            flag  = (int*)ws;           ws += (size_t)32768 * 4;         // 128 KB
  int*            tick  = (int*)ws;           ws += 64 * 4;

  zero_flags<<<128, 256, 0, stream>>>(flag, tick);
  wcast4<<<1024, 256, 0, stream>>>(Wi_x, Wf_x, Wo_x, Wu_x, Wxbf);
  whpack<<<512, 256, 0, stream>>>(Wi_h, Wf_h, Wo_h, Wu_h, Whp);
  levels_k<<<1, 128, 0, stream>>>(parents, pairs, lmeta, mrows);
  dim3 g1(512, 32);
  xproj<<<g1, 256, 0, stream>>>(X, Wxbf, bi_x, bi_h, bf_x, bf_h, Xpre);

  treelstm_flag<<<512, 256, 0, stream>>>(Xpre, Whp, parents, pairs, lmeta,
                                         mrows, flag, tick, Hout, Cbuf, Hbf);
}

// Round 5
// 820.790 us; speedup vs baseline: 5.1867x; 5.1867x over previous
//
#include <hip/hip_runtime.h>
#include <hip/hip_bf16.h>

static constexpr int LL = 256;   // sequence length / nodes
static constexpr int BB = 128;   // batch
static constexpr int HHH = 512;  // hidden dim

typedef __attribute__((ext_vector_type(8))) short bf16x8;
typedef __attribute__((ext_vector_type(4))) float f32x4;
typedef __attribute__((ext_vector_type(8))) unsigned short u16x8;
typedef __attribute__((ext_vector_type(4))) unsigned short u16x4;

__device__ __forceinline__ unsigned short f2bf(float f) {
  union { float f; unsigned u; } v; v.f = f;
  unsigned r = (v.u + 0x7FFFu + ((v.u >> 16) & 1u)) >> 16;
  return (unsigned short)r;
}
__device__ __forceinline__ float bf2f(unsigned short s) {
  union { unsigned u; float f; } v; v.u = ((unsigned)s) << 16;
  return v.f;
}
__device__ __forceinline__ float sigm(float x) { return 1.0f / (1.0f + __expf(-x)); }
__device__ __forceinline__ float tanh_f(float x) { return 1.0f - 2.0f / (__expf(2.0f * x) + 1.0f); }

// ---------------------------------------------------------------------------
// Kernel 0: zero the per-node completion flags + ticket counters (every call).
// ---------------------------------------------------------------------------
__global__ __launch_bounds__(256) void zero_flags(int* __restrict__ flag,
                                                  int* __restrict__ tick) {
  int i = blockIdx.x * 256 + threadIdx.x;
  if (i < LL * BB) flag[i] = 0;
  if (i < 16) tick[i] = 0;
}

// ---------------------------------------------------------------------------
// Kernel 1a: cast the 4 x-weight matrices to bf16 (row-major, K-major rows).
// ---------------------------------------------------------------------------
__global__ __launch_bounds__(256) void wcast4(
    const float* __restrict__ s0, const float* __restrict__ s1,
    const float* __restrict__ s2, const float* __restrict__ s3,
    unsigned short* __restrict__ wx) {
  int gid = blockIdx.x * 256 + threadIdx.x;
  int e = gid * 4;
  int m = e >> 18;            // which of 4 matrices (512*512 elems each)
  int off = e & 0x3FFFF;
  const float* srcs[4] = {s0, s1, s2, s3};
  float4 v = *(const float4*)(srcs[m] + off);
  u16x4 o;
  o[0] = f2bf(v.x); o[1] = f2bf(v.y); o[2] = f2bf(v.z); o[3] = f2bf(v.w);
  *(u16x4*)(wx + (size_t)m * 262144 + off) = o;
}

// ---------------------------------------------------------------------------
// Kernel 1b: pack the 4 h-weight matrices into MFMA B-fragment order (bf16).
// Whp block id = (g*32 + n16)*16 + kb, each block = 64 lanes * 8 bf16 = 1KB;
// lane l holds W[g][n16*16 + (l&15)][kb*32 + (l>>4)*8 + 0..7].
// ---------------------------------------------------------------------------
__global__ __launch_bounds__(256) void whpack(
    const float* __restrict__ Wi_h, const float* __restrict__ Wf_h,
    const float* __restrict__ Wo_h, const float* __restrict__ Wu_h,
    unsigned short* __restrict__ Whp) {
  int gid = blockIdx.x * 256 + threadIdx.x;   // 131072 threads total
  int lane = gid & 63;
  int kb   = (gid >> 6) & 15;
  int n16  = (gid >> 10) & 31;
  int g    = gid >> 15;
  const float* W = (g == 0) ? Wi_h : (g == 1) ? Wf_h : (g == 2) ? Wo_h : Wu_h;
  int row = n16 * 16 + (lane & 15);
  int col = kb * 32 + (lane >> 4) * 8;
  const float4* s = (const float4*)(W + (size_t)row * 512 + col);
  float4 v0 = s[0], v1 = s[1];
  u16x8 o;
  o[0] = f2bf(v0.x); o[1] = f2bf(v0.y); o[2] = f2bf(v0.z); o[3] = f2bf(v0.w);
  o[4] = f2bf(v1.x); o[5] = f2bf(v1.y); o[6] = f2bf(v1.z); o[7] = f2bf(v1.w);
  *(u16x8*)&Whp[(size_t)gid * 8] = o;
}

// ---------------------------------------------------------------------------
// Kernel 2: level assignment + bucketing + tile-list emission.
// One block, 128 threads (one per batch column).
// pairs: node ids (t*128+b) grouped by level (topological order).
// mrows[i] = (rbase << 6) | rcnt for each 32-row tile, in level order.
// lmeta[0] = number of tiles (mcnt).
// ---------------------------------------------------------------------------
__global__ __launch_bounds__(128) void levels_k(
    const int* __restrict__ parents, int* __restrict__ pairs,
    int* __restrict__ lmeta, int* __restrict__ mrows) {
  __shared__ unsigned short cnt2[128][130];  // per (b, level) counts -> starts
  __shared__ int off[130];
  __shared__ int maxl_sh;
  const int b = threadIdx.x;
  unsigned char mylvl[256];                  // private per-column levels
  for (int l = 0; l < 130; ++l) cnt2[b][l] = 0;
  if (b == 0) maxl_sh = 0;
  __syncthreads();
  int maxl = 0;
  for (int t = 0; t < 256; ++t) {
    int p = parents[t * 128 + b];
    int l = (p < 0) ? 0 : (mylvl[p] + 1);
    if (l > 127) l = 127;                    // safety clamp
    mylvl[t] = (unsigned char)l;
    maxl = l > maxl ? l : maxl;
    cnt2[b][l]++;
  }
  atomicMax(&maxl_sh, maxl);
  __syncthreads();
  const int nlev = maxl_sh + 1;
  {
    int l = b;
    int s = 0;
    if (l < nlev) for (int bb = 0; bb < 128; ++bb) s += cnt2[bb][l];
    off[l + 1] = s;
  }
  __syncthreads();
  if (b == 0) {
    off[0] = 0;
    for (int l = 0; l < 128; ++l) off[l + 1] += off[l];
  }
  __syncthreads();
  {
    int l = b;
    if (l < nlev) {
      int run = off[l];
      for (int bb = 0; bb < 128; ++bb) {
        int c = cnt2[bb][l];
        cnt2[bb][l] = (unsigned short)run;
        run += c;
      }
    }
  }
  __syncthreads();
  for (int t = 0; t < 256; ++t) {
    int l = mylvl[t];
    int pos = cnt2[b][l]++;
    pairs[pos] = t * 128 + b;
  }
  if (b == 0) {
    int midx = 0;
    for (int l = 0; l < nlev; ++l) {
      int s = off[l], e = off[l + 1];
      for (int rb = s; rb < e; rb += 32) {
        int rc = (e - rb < 32) ? (e - rb) : 32;
        mrows[midx++] = (rb << 6) | rc;
      }
    }
    lmeta[0] = midx;
  }
}

// ---------------------------------------------------------------------------
// Kernel 3: Xpre[t*B+b][g*512+h] = x[t,b,:] . Wg_x[h,:] + bias_g[h]   (bf16)
// GEMM M=32768 N=2048 K=512.  64x64 tile, BK=64, 4 waves.
// ---------------------------------------------------------------------------
__global__ __launch_bounds__(256) void xproj(
    const float* __restrict__ X, const unsigned short* __restrict__ Wx,
    const float* __restrict__ bi_x, const float* __restrict__ bi_h,
    const float* __restrict__ bf_x, const float* __restrict__ bf_h,
    unsigned short* __restrict__ Xpre) {
  __shared__ unsigned short As[64][72];
  __shared__ unsigned short Bs[64][72];
  const int m0 = blockIdx.x * 64;
  const int n0 = blockIdx.y * 64;
  const int tid = threadIdx.x;
  const int r = tid >> 2, c4 = tid & 3;
  const int lane = tid & 63, w = tid >> 6;
  f32x4 acc[4] = {};
  for (int kt = 0; kt < 8; ++kt) {
    const int k0 = kt * 64;
    __syncthreads();
    {
      const float* src = X + (size_t)(m0 + r) * 512 + k0 + c4 * 16;
      float4 v0 = ((const float4*)src)[0];
      float4 v1 = ((const float4*)src)[1];
      float4 v2 = ((const float4*)src)[2];
      float4 v3 = ((const float4*)src)[3];
      u16x8 p0, p1;
      p0[0] = f2bf(v0.x); p0[1] = f2bf(v0.y); p0[2] = f2bf(v0.z); p0[3] = f2bf(v0.w);
      p0[4] = f2bf(v1.x); p0[5] = f2bf(v1.y); p0[6] = f2bf(v1.z); p0[7] = f2bf(v1.w);
      p1[0] = f2bf(v2.x); p1[1] = f2bf(v2.y); p1[2] = f2bf(v2.z); p1[3] = f2bf(v2.w);
      p1[4] = f2bf(v3.x); p1[5] = f2bf(v3.y); p1[6] = f2bf(v3.z); p1[7] = f2bf(v3.w);
      *(u16x8*)&As[r][c4 * 16] = p0;
      *(u16x8*)&As[r][c4 * 16 + 8] = p1;
      const unsigned short* sb = Wx + (size_t)(n0 + r) * 512 + k0 + c4 * 16;
      u16x8 q0 = ((const u16x8*)sb)[0];
      u16x8 q1 = ((const u16x8*)sb)[1];
      *(u16x8*)&Bs[r][c4 * 16] = q0;
      *(u16x8*)&Bs[r][c4 * 16 + 8] = q1;
    }
    __syncthreads();
#pragma unroll
    for (int kk = 0; kk < 64; kk += 32) {
      const int ko = kk + 8 * (lane >> 4);
      bf16x8 af = *(const bf16x8*)&As[w * 16 + (lane & 15)][ko];
#pragma unroll
      for (int n = 0; n < 4; ++n) {
        bf16x8 bfr = *(const bf16x8*)&Bs[n * 16 + (lane & 15)][ko];
        acc[n] = __builtin_amdgcn_mfma_f32_16x16x32_bf16(af, bfr, acc[n], 0, 0, 0);
      }
    }
  }
#pragma unroll
  for (int n = 0; n < 4; ++n) {
    const int gcol = n0 + n * 16 + (lane & 15);
    const int g = gcol >> 9, hh = gcol & 511;
    float badd = 0.0f;
    if (g == 0) badd = bi_x[hh] + bi_h[hh];
    else if (g == 1) badd = bf_x[hh] + bf_h[hh];
    const int rbase = m0 + w * 16 + (lane >> 4) * 4;
#pragma unroll
    for (int q = 0; q < 4; ++q) {
      Xpre[(size_t)(rbase + q) * 2048 + gcol] = f2bf(acc[n][q] + badd);
    }
  }
}

// ---------------------------------------------------------------------------
// Kernel 4: recurrence via per-node readiness flags + per-ct ticket queues.
// Fence-free protocol:
//  - producers write Hbf/Cbuf THROUGH to LLC (8B relaxed agent atomic stores,
//    sc1: never dirty in L2 -> no writeback fence needed anywhere)
//  - flag increment: relaxed agent RMW, after s_waitcnt vmcnt(0) (the adding
//    wave contains all 8 threads of its rows, so its drain covers them)
//  - consumers poll with RELAXED agent loads (no L2-invalidate storms),
//    32 lanes of wave 0 only, s_sleep backoff; data gathers are normal
//    vector loads (lines only ever read after the LLC-visible write).
// ---------------------------------------------------------------------------
__global__ __launch_bounds__(256, 2) void treelstm_flag(
    const unsigned short* __restrict__ Xpre,  // [L*B][2048]
    const unsigned short* __restrict__ Whp,   // packed [4][32][16][512]
    const int* __restrict__ parents,          // [L][B]
    const int* __restrict__ pairs,            // [32768] node ids by level
    const int* __restrict__ lmeta,            // [0] = mcnt
    const int* __restrict__ mrows,            // tile list (rbase<<6 | rcnt)
    int* __restrict__ flag,                   // [32768] completion counters
    int* __restrict__ tick,                   // [16] ticket counters
    float* __restrict__ Hout,                 // [B][L][H]  (d_out)
    float* __restrict__ Cbuf,                 // [B][L][H]
    unsigned short* __restrict__ Hbf) {       // [B][L][H] bf16
  __shared__ unsigned short phs[32][536];     // 34.3KB (round-2 proven layout)
  __shared__ float gbuf[4][32][33];           // 16.9KB
  __shared__ int sh_ticket;
  const int tid = threadIdx.x;
  const int lane = tid & 63, w = tid >> 6;
  const int ct = blockIdx.x & 15;
  const int c0 = ct * 32;
  const int mcnt = lmeta[0];

  // ---- preload weights for (gate w, cols c0..c0+31) into registers ----
  bf16x8 wfrag[2][16];
  {
    const size_t base = (size_t)((w * 32 + ct * 2) * 16) * 512 + lane * 8;
#pragma unroll
    for (int kb = 0; kb < 16; ++kb) {
      wfrag[0][kb] = *(const bf16x8*)&Whp[base + (size_t)kb * 512];
      wfrag[1][kb] = *(const bf16x8*)&Whp[base + (size_t)(16 + kb) * 512];
    }
  }

  while (true) {
    __syncthreads();   // protect sh_ticket / phs / gbuf from previous iter
    if (tid == 0) sh_ticket = atomicAdd(&tick[ct], 1);
    __syncthreads();
    const int my = sh_ticket;
    if (my >= mcnt) break;
    const int mr = mrows[my];
    const int rbase = mr >> 6;
    const int rcnt = mr & 63;

    // ---- phase A: wave-0 lanes poll readiness (relaxed, no cache ops) ----
    if (tid < 32) {
      int pn = -1;
      if (tid < rcnt) {
        const int node2 = pairs[rbase + tid];
        const int p2 = parents[node2];
        if (p2 >= 0) pn = p2 * 128 + (node2 & 127);
      }
      if (pn >= 0) {
        while (__hip_atomic_load(&flag[pn], __ATOMIC_RELAXED,
                                 __HIP_MEMORY_SCOPE_AGENT) < 16)
          __builtin_amdgcn_s_sleep(4);
      }
    }
    __syncthreads();

    // ---- phase B: gather parent h rows (bf16) into LDS ----
    const int r = tid >> 3;   // 0..31
    const int q = tid & 7;    // 64 bf16 each
    int node = 0, p = -1, b = 0;
    if (r < rcnt) {
      node = pairs[rbase + r];
      p = parents[node];
      b = node & 127;
    }
    if (p >= 0) {
      const unsigned short* src = Hbf + ((size_t)b * LL + p) * HHH + q * 64;
#pragma unroll
      for (int j = 0; j < 8; ++j)
        *(u16x8*)&phs[r][q * 64 + j * 8] = ((const u16x8*)src)[j];
    } else {
      u16x8 z = {};
#pragma unroll
      for (int j = 0; j < 8; ++j) *(u16x8*)&phs[r][q * 64 + j * 8] = z;
    }
    __syncthreads();

    // ---- phase C: wave w computes gate w, 32x32, K=512 (weights in regs) --
    f32x4 acc[2][2] = {};
    const int hi = lane >> 4;
#pragma unroll
    for (int kb = 0; kb < 16; ++kb) {
      const int ko = kb * 32 + 8 * hi;
      bf16x8 a0 = *(const bf16x8*)&phs[lane & 15][ko];
      bf16x8 a1 = *(const bf16x8*)&phs[16 + (lane & 15)][ko];
      acc[0][0] = __builtin_amdgcn_mfma_f32_16x16x32_bf16(a0, wfrag[0][kb], acc[0][0], 0, 0, 0);
      acc[1][0] = __builtin_amdgcn_mfma_f32_16x16x32_bf16(a1, wfrag[0][kb], acc[1][0], 0, 0, 0);
      acc[0][1] = __builtin_amdgcn_mfma_f32_16x16x32_bf16(a0, wfrag[1][kb], acc[0][1], 0, 0, 0);
      acc[1][1] = __builtin_amdgcn_mfma_f32_16x16x32_bf16(a1, wfrag[1][kb], acc[1][1], 0, 0, 0);
    }
#pragma unroll
    for (int mi = 0; mi < 2; ++mi)
#pragma unroll
      for (int ni = 0; ni < 2; ++ni)
#pragma unroll
        for (int qq = 0; qq < 4; ++qq)
          gbuf[w][mi * 16 + (lane >> 4) * 4 + qq][ni * 16 + (lane & 15)] = acc[mi][ni][qq];
    __syncthreads();

    // ---- phase D: elementwise gates; communicated stores go through LLC ---
    if (r < rcnt) {
      const int hc = q * 4;
      const int t = node >> 7;
      const int h = c0 + hc;
      float4 pc = make_float4(0.f, 0.f, 0.f, 0.f);
      if (p >= 0) pc = *(const float4*)(Cbuf + ((size_t)b * LL + p) * HHH + h);
      float xg[4][4];
#pragma unroll
      for (int g = 0; g < 4; ++g) {
        u16x4 xv = *(const u16x4*)(Xpre + (size_t)node * 2048 + g * 512 + h);
#pragma unroll
        for (int j = 0; j < 4; ++j) xg[g][j] = bf2f(xv[j]);
      }
      const float pcv[4] = {pc.x, pc.y, pc.z, pc.w};
      float cva[4], hva[4];
#pragma unroll
      for (int j = 0; j < 4; ++j) {
        float iv = sigm(gbuf[0][r][hc + j] + xg[0][j]);
        float fv = sigm(gbuf[1][r][hc + j] + xg[1][j]);
        float ov = sigm(gbuf[2][r][hc + j] + xg[2][j]);
        float uv = tanh_f(gbuf[3][r][hc + j] + xg[3][j]);
        float cv = iv * uv + fv * pcv[j];
        cva[j] = cv;
        hva[j] = ov * tanh_f(cv);
      }
      const size_t obase = ((size_t)b * LL + t) * HHH + h;
      // Hout: pure output, normal store
      *(float4*)(Hout + obase) = make_float4(hva[0], hva[1], hva[2], hva[3]);
      // Cbuf, Hbf: consumed by other WGs -> store through to LLC (sc1)
      union { float f[4]; unsigned long long u[2]; } cvu;
      cvu.f[0] = cva[0]; cvu.f[1] = cva[1]; cvu.f[2] = cva[2]; cvu.f[3] = cva[3];
      unsigned long long* cp = (unsigned long long*)(Cbuf + obase);
      __hip_atomic_store(cp, cvu.u[0], __ATOMIC_RELAXED, __HIP_MEMORY_SCOPE_AGENT);
      __hip_atomic_store(cp + 1, cvu.u[1], __ATOMIC_RELAXED, __HIP_MEMORY_SCOPE_AGENT);
      union { unsigned short s[4]; unsigned long long u; } hbu;
      hbu.s[0] = f2bf(hva[0]); hbu.s[1] = f2bf(hva[1]);
      hbu.s[2] = f2bf(hva[2]); hbu.s[3] = f2bf(hva[3]);
      __hip_atomic_store((unsigned long long*)(Hbf + obase), hbu.u,
                         __ATOMIC_RELAXED, __HIP_MEMORY_SCOPE_AGENT);
    }
    // drain this wave's LLC stores (covers all 8 threads of each of its rows)
    asm volatile("s_waitcnt vmcnt(0)" ::: "memory");
    if (r < rcnt && q == 0)
      __hip_atomic_fetch_add(&flag[node], 1, __ATOMIC_RELAXED,
                             __HIP_MEMORY_SCOPE_AGENT);
  }
}

// ---------------------------------------------------------------------------
extern "C" void kernel_launch(void* const* d_in, const int* in_sizes, int n_in,
                              void* d_out, int out_size, void* d_ws, size_t ws_size,
                              hipStream_t stream) {
  const float* X    = (const float*)d_in[0];
  const float* Wi_x = (const float*)d_in[1];
  const float* bi_x = (const float*)d_in[2];
  const float* Wi_h = (const float*)d_in[3];
  const float* bi_h = (const float*)d_in[4];
  const float* Wf_x = (const float*)d_in[5];
  const float* bf_x = (const float*)d_in[6];
  const float* Wf_h = (const float*)d_in[7];
  const float* bf_h = (const float*)d_in[8];
  const float* Wo_x = (const float*)d_in[9];
  const float* Wo_h = (const float*)d_in[10];
  const float* Wu_x = (const float*)d_in[11];
  const float* Wu_h = (const float*)d_in[12];
  const int* parents = (const int*)d_in[13];
  float* Hout = (float*)d_out;

  char* ws = (char*)d_ws;
  unsigned short* Xpre = (unsigned short*)ws; ws += (size_t)32768 * 2048 * 2;  // 128 MB
  unsigned short* Hbf  = (unsigned short*)ws; ws += (size_t)BB * LL * HHH * 2; // 32 MB
  float*          Cbuf = (float*)ws;          ws += (size_t)BB * LL * HHH * 4; // 64 MB
  unsigned short* Wxbf = (unsigned short*)ws; ws += (size_t)2048 * 512 * 2;    // 2 MB
  unsigned short* Whp  = (unsigned short*)ws; ws += (size_t)2048 * 512 * 2;    // 2 MB
  int*            pairs = (int*)ws;           ws += (size_t)32768 * 4;         // 128 KB
  int*            lmeta = (int*)ws;           ws += 256 * 4;
  int*            mrows = (int*)ws;           ws += 4096 * 4;
  int*            flag  = (int*)ws;           ws += (size_t)32768 * 4;         // 128 KB
  int*            tick  = (int*)ws;           ws += 64 * 4;

  zero_flags<<<128, 256, 0, stream>>>(flag, tick);
  wcast4<<<1024, 256, 0, stream>>>(Wi_x, Wf_x, Wo_x, Wu_x, Wxbf);
  whpack<<<512, 256, 0, stream>>>(Wi_h, Wf_h, Wo_h, Wu_h, Whp);
  levels_k<<<1, 128, 0, stream>>>(parents, pairs, lmeta, mrows);
  dim3 g1(512, 32);
  xproj<<<g1, 256, 0, stream>>>(X, Wxbf, bi_x, bi_h, bf_x, bf_h, Xpre);

  treelstm_flag<<<512, 256, 0, stream>>>(Xpre, Whp, parents, pairs, lmeta,
                                         mrows, flag, tick, Hout, Cbuf, Hbf);
}

// Round 7
// 589.992 us; speedup vs baseline: 7.2156x; 1.3912x over previous
//
#include <hip/hip_runtime.h>
#include <hip/hip_bf16.h>

static constexpr int LL = 256;   // sequence length / nodes
static constexpr int BB = 128;   // batch
static constexpr int HHH = 512;  // hidden dim

typedef __attribute__((ext_vector_type(8))) short bf16x8;
typedef __attribute__((ext_vector_type(4))) float f32x4;
typedef __attribute__((ext_vector_type(8))) unsigned short u16x8;
typedef __attribute__((ext_vector_type(4))) unsigned short u16x4;

__device__ __forceinline__ unsigned short f2bf(float f) {
  union { float f; unsigned u; } v; v.f = f;
  unsigned r = (v.u + 0x7FFFu + ((v.u >> 16) & 1u)) >> 16;
  return (unsigned short)r;
}
__device__ __forceinline__ float bf2f(unsigned short s) {
  union { unsigned u; float f; } v; v.u = ((unsigned)s) << 16;
  return v.f;
}
__device__ __forceinline__ float sigm(float x) { return 1.0f / (1.0f + __expf(-x)); }
__device__ __forceinline__ float tanh_f(float x) { return 1.0f - 2.0f / (__expf(2.0f * x) + 1.0f); }

// ---------------------------------------------------------------------------
// Kernel 0: zero the per-node completion flags + ticket counters (every call).
// ---------------------------------------------------------------------------
__global__ __launch_bounds__(256) void zero_flags(int* __restrict__ flag,
                                                  int* __restrict__ tick) {
  int i = blockIdx.x * 256 + threadIdx.x;
  if (i < LL * BB) flag[i] = 0;
  if (i < 16) tick[i] = 0;
}

// ---------------------------------------------------------------------------
// Kernel 1a: cast the 4 x-weight matrices to bf16 (row-major, K-major rows).
// ---------------------------------------------------------------------------
__global__ __launch_bounds__(256) void wcast4(
    const float* __restrict__ s0, const float* __restrict__ s1,
    const float* __restrict__ s2, const float* __restrict__ s3,
    unsigned short* __restrict__ wx) {
  int gid = blockIdx.x * 256 + threadIdx.x;
  int e = gid * 4;
  int m = e >> 18;            // which of 4 matrices (512*512 elems each)
  int off = e & 0x3FFFF;
  const float* srcs[4] = {s0, s1, s2, s3};
  float4 v = *(const float4*)(srcs[m] + off);
  u16x4 o;
  o[0] = f2bf(v.x); o[1] = f2bf(v.y); o[2] = f2bf(v.z); o[3] = f2bf(v.w);
  *(u16x4*)(wx + (size_t)m * 262144 + off) = o;
}

// ---------------------------------------------------------------------------
// Kernel 1b: cast inputs X (L*B*D f32) to bf16.
// ---------------------------------------------------------------------------
__global__ __launch_bounds__(256) void xcast(
    const float* __restrict__ X, unsigned short* __restrict__ Xbf) {
  size_t base = ((size_t)blockIdx.x * 256 + threadIdx.x) * 8;
  float4 v0 = *(const float4*)(X + base);
  float4 v1 = *(const float4*)(X + base + 4);
  u16x8 o;
  o[0] = f2bf(v0.x); o[1] = f2bf(v0.y); o[2] = f2bf(v0.z); o[3] = f2bf(v0.w);
  o[4] = f2bf(v1.x); o[5] = f2bf(v1.y); o[6] = f2bf(v1.z); o[7] = f2bf(v1.w);
  *(u16x8*)(Xbf + base) = o;
}

// ---------------------------------------------------------------------------
// Kernel 1c: pack the 4 h-weight matrices into MFMA B-fragment order (bf16).
// Whp block id = (g*32 + n16)*16 + kb, each block = 64 lanes * 8 bf16 = 1KB;
// lane l holds W[g][n16*16 + (l&15)][kb*32 + (l>>4)*8 + 0..7].
// ---------------------------------------------------------------------------
__global__ __launch_bounds__(256) void whpack(
    const float* __restrict__ Wi_h, const float* __restrict__ Wf_h,
    const float* __restrict__ Wo_h, const float* __restrict__ Wu_h,
    unsigned short* __restrict__ Whp) {
  int gid = blockIdx.x * 256 + threadIdx.x;   // 131072 threads total
  int lane = gid & 63;
  int kb   = (gid >> 6) & 15;
  int n16  = (gid >> 10) & 31;
  int g    = gid >> 15;
  const float* W = (g == 0) ? Wi_h : (g == 1) ? Wf_h : (g == 2) ? Wo_h : Wu_h;
  int row = n16 * 16 + (lane & 15);
  int col = kb * 32 + (lane >> 4) * 8;
  const float4* s = (const float4*)(W + (size_t)row * 512 + col);
  float4 v0 = s[0], v1 = s[1];
  u16x8 o;
  o[0] = f2bf(v0.x); o[1] = f2bf(v0.y); o[2] = f2bf(v0.z); o[3] = f2bf(v0.w);
  o[4] = f2bf(v1.x); o[5] = f2bf(v1.y); o[6] = f2bf(v1.z); o[7] = f2bf(v1.w);
  *(u16x8*)&Whp[(size_t)gid * 8] = o;
}

// ---------------------------------------------------------------------------
// Kernel 2: level assignment + bucketing + tile-list emission.
// One block, 128 threads (one per batch column).
// ---------------------------------------------------------------------------
__global__ __launch_bounds__(128) void levels_k(
    const int* __restrict__ parents, int* __restrict__ pairs,
    int* __restrict__ lmeta, int* __restrict__ mrows) {
  __shared__ unsigned short cnt2[128][130];
  __shared__ int off[130];
  __shared__ int maxl_sh;
  const int b = threadIdx.x;
  unsigned char mylvl[256];
  for (int l = 0; l < 130; ++l) cnt2[b][l] = 0;
  if (b == 0) maxl_sh = 0;
  __syncthreads();
  int maxl = 0;
  for (int t = 0; t < 256; ++t) {
    int p = parents[t * 128 + b];
    int l = (p < 0) ? 0 : (mylvl[p] + 1);
    if (l > 127) l = 127;
    mylvl[t] = (unsigned char)l;
    maxl = l > maxl ? l : maxl;
    cnt2[b][l]++;
  }
  atomicMax(&maxl_sh, maxl);
  __syncthreads();
  const int nlev = maxl_sh + 1;
  {
    int l = b;
    int s = 0;
    if (l < nlev) for (int bb = 0; bb < 128; ++bb) s += cnt2[bb][l];
    off[l + 1] = s;
  }
  __syncthreads();
  if (b == 0) {
    off[0] = 0;
    for (int l = 0; l < 128; ++l) off[l + 1] += off[l];
  }
  __syncthreads();
  {
    int l = b;
    if (l < nlev) {
      int run = off[l];
      for (int bb = 0; bb < 128; ++bb) {
        int c = cnt2[bb][l];
        cnt2[bb][l] = (unsigned short)run;
        run += c;
      }
    }
  }
  __syncthreads();
  for (int t = 0; t < 256; ++t) {
    int l = mylvl[t];
    int pos = cnt2[b][l]++;
    pairs[pos] = t * 128 + b;
  }
  if (b == 0) {
    int midx = 0;
    for (int l = 0; l < nlev; ++l) {
      int s = off[l], e = off[l + 1];
      for (int rb = s; rb < e; rb += 32) {
        int rc = (e - rb < 32) ? (e - rb) : 32;
        mrows[midx++] = (rb << 6) | rc;
      }
    }
    lmeta[0] = midx;
  }
}

// ---------------------------------------------------------------------------
// Kernel 3: Xpre = Xbf @ Wx^T + bias   (bf16 in/out)
// GEMM M=32768 N=2048 K=512.  128x128 tile, BK=64, 4 waves (64x64 each),
// global_load_lds width-16, both-sides XOR swizzle (elem ^= (row&7)<<3).
// ---------------------------------------------------------------------------
__global__ __launch_bounds__(256) void xproj2(
    const unsigned short* __restrict__ Xbf, const unsigned short* __restrict__ Wx,
    const float* __restrict__ bi_x, const float* __restrict__ bi_h,
    const float* __restrict__ bf_x, const float* __restrict__ bf_h,
    unsigned short* __restrict__ Xpre) {
  __shared__ unsigned short As[128 * 64];   // 16 KB, linear (gload_lds dest)
  __shared__ unsigned short Bs[128 * 64];   // 16 KB
  const int m0 = blockIdx.x * 128;
  const int n0 = blockIdx.y * 128;
  const int tid = threadIdx.x;
  const int lane = tid & 63, w = tid >> 6;
  const int wr = w >> 1, wc = w & 1;
  const int hi = lane >> 4, l15 = lane & 15;
  f32x4 acc[4][4] = {};
  for (int kt = 0; kt < 8; ++kt) {
    const int k0 = kt * 64;
    __syncthreads();
#pragma unroll
    for (int i = 0; i < 4; ++i) {
      const int grp = i * 4 + w;               // 0..15
      const int unit = grp * 64 + lane;        // 0..1023
      const int row = unit >> 3, c8p = unit & 7;
      const int c8l = c8p ^ (row & 7);         // inverse swizzle on SOURCE
      const unsigned short* ga = Xbf + (size_t)(m0 + row) * 512 + k0 + c8l * 8;
      __builtin_amdgcn_global_load_lds(
          (const __attribute__((address_space(1))) unsigned int*)ga,
          (__attribute__((address_space(3))) unsigned int*)(As + grp * 512),
          16, 0, 0);
      const unsigned short* gb = Wx + (size_t)(n0 + row) * 512 + k0 + c8l * 8;
      __builtin_amdgcn_global_load_lds(
          (const __attribute__((address_space(1))) unsigned int*)gb,
          (__attribute__((address_space(3))) unsigned int*)(Bs + grp * 512),
          16, 0, 0);
    }
    __syncthreads();
#pragma unroll
    for (int kk = 0; kk < 2; ++kk) {
      const int kofs = kk * 32 + hi * 8;
      bf16x8 a[4], bb[4];
#pragma unroll
      for (int mi = 0; mi < 4; ++mi) {
        const int row = wr * 64 + mi * 16 + l15;
        a[mi] = *(const bf16x8*)&As[row * 64 + (kofs ^ ((row & 7) << 3))];
      }
#pragma unroll
      for (int ni = 0; ni < 4; ++ni) {
        const int row = wc * 64 + ni * 16 + l15;
        bb[ni] = *(const bf16x8*)&Bs[row * 64 + (kofs ^ ((row & 7) << 3))];
      }
#pragma unroll
      for (int mi = 0; mi < 4; ++mi)
#pragma unroll
        for (int ni = 0; ni < 4; ++ni)
          acc[mi][ni] = __builtin_amdgcn_mfma_f32_16x16x32_bf16(a[mi], bb[ni], acc[mi][ni], 0, 0, 0);
    }
  }
#pragma unroll
  for (int ni = 0; ni < 4; ++ni) {
    const int col = n0 + wc * 64 + ni * 16 + l15;
    const int g = col >> 9, hh = col & 511;
    float badd = 0.0f;
    if (g == 0) badd = bi_x[hh] + bi_h[hh];
    else if (g == 1) badd = bf_x[hh] + bf_h[hh];
#pragma unroll
    for (int mi = 0; mi < 4; ++mi) {
      const int rbase = m0 + wr * 64 + mi * 16 + hi * 4;
#pragma unroll
      for (int q = 0; q < 4; ++q)
        Xpre[(size_t)(rbase + q) * 2048 + col] = f2bf(acc[mi][ni][q] + badd);
    }
  }
}

// ---------------------------------------------------------------------------
// Kernel 4: recurrence via per-node readiness flags + per-ct ticket queues.
// 512 threads (8 waves): wave w -> gate w&3, col-half w>>2; WG ct=blockIdx&7
// owns cols [ct*64, ct*64+64) of all 4 gates.  Weights stationary in regs
// (128 VGPR/wave, asm keep-alive defeats rematerialization).  flag[node]
// counts completed col-tiles, ready at 8.  Fence-free LLC protocol (sc1
// write-through producers, relaxed polls) as validated in round 5.
// ---------------------------------------------------------------------------
__global__ __launch_bounds__(512, 2) void treelstm_flag(
    const unsigned short* __restrict__ Xpre,  // [L*B][2048]
    const unsigned short* __restrict__ Whp,   // packed [4][32][16][512]
    const int* __restrict__ parents,          // [L][B]
    const int* __restrict__ pairs,            // [32768] node ids by level
    const int* __restrict__ lmeta,            // [0] = mcnt
    const int* __restrict__ mrows,            // tile list (rbase<<6 | rcnt)
    int* __restrict__ flag,                   // [32768] completion counters
    int* __restrict__ tick,                   // [8] ticket counters
    float* __restrict__ Hout,                 // [B][L][H]  (d_out)
    float* __restrict__ Cbuf,                 // [B][L][H]
    unsigned short* __restrict__ Hbf) {       // [B][L][H] bf16
  __shared__ unsigned short phs[32][536];     // 34.3KB
  __shared__ float gbuf[4][32][66];           // 33.8KB
  __shared__ int sh_ticket;
  const int tid = threadIdx.x;
  const int lane = tid & 63, w = tid >> 6;
  const int g = w & 3, nh = w >> 2;
  const int ct = blockIdx.x & 7;
  const int mcnt = lmeta[0];
  const int hi = lane >> 4, l15 = lane & 15;

  // ---- preload weights for (gate g, cols ct*64+nh*32 ..+32) into regs ----
  bf16x8 wfrag[2][16];
  {
    const size_t base = (size_t)((g * 32 + ct * 4 + nh * 2) * 16) * 512 + lane * 8;
#pragma unroll
    for (int kb = 0; kb < 16; ++kb) {
      wfrag[0][kb] = *(const bf16x8*)&Whp[base + (size_t)kb * 512];
      wfrag[1][kb] = *(const bf16x8*)&Whp[base + (size_t)(16 + kb) * 512];
    }
  }
  // keep-alive: values become opaque -> compiler cannot rematerialize from
  // global memory; forces true register residency (expect ~200 VGPRs).
#pragma unroll
  for (int kb = 0; kb < 16; ++kb) {
    asm volatile("" : "+v"(wfrag[0][kb]));
    asm volatile("" : "+v"(wfrag[1][kb]));
  }

  while (true) {
    __syncthreads();   // protect sh_ticket / phs / gbuf from previous iter
    if (tid == 0) sh_ticket = atomicAdd(&tick[ct], 1);
    __syncthreads();
    const int my = sh_ticket;
    if (my >= mcnt) break;
    const int mr = mrows[my];
    const int rbase = mr >> 6;
    const int rcnt = mr & 63;

    // thread -> (row r = tid>>4, chunk q16 = tid&15); same mapping for
    // gather and epilogue.
    const int r = tid >> 4;
    const int q16 = tid & 15;
    const int hc = q16 * 4;            // epilogue col offset within 64
    const int h = ct * 64 + hc;
    int node = 0, p = -1, b = 0;
    if (r < rcnt) {
      node = pairs[rbase + r];
      p = parents[node];
      b = node & 127;
    }
    // prefetch Xpre gate pre-activations (no dependency on parents)
    u16x4 xga[4] = {};
    if (r < rcnt) {
#pragma unroll
      for (int gg = 0; gg < 4; ++gg)
        xga[gg] = *(const u16x4*)(Xpre + (size_t)node * 2048 + gg * 512 + h);
    }

    // ---- phase A: wave-0 lanes poll readiness (relaxed, no cache ops) ----
    if (tid < 32) {
      int pn = -1;
      if (tid < rcnt) {
        const int node2 = pairs[rbase + tid];
        const int p2 = parents[node2];
        if (p2 >= 0) pn = p2 * 128 + (node2 & 127);
      }
      if (pn >= 0) {
        while (__hip_atomic_load(&flag[pn], __ATOMIC_RELAXED,
                                 __HIP_MEMORY_SCOPE_AGENT) < 8)
          __builtin_amdgcn_s_sleep(1);
      }
    }
    __syncthreads();

    // prefetch parent c (valid now), and gather parent h rows into LDS
    float4 pc = make_float4(0.f, 0.f, 0.f, 0.f);
    if (r < rcnt && p >= 0)
      pc = *(const float4*)(Cbuf + ((size_t)b * LL + p) * HHH + h);
    if (p >= 0) {
      const unsigned short* src = Hbf + ((size_t)b * LL + p) * HHH + q16 * 32;
#pragma unroll
      for (int j = 0; j < 4; ++j)
        *(u16x8*)&phs[r][q16 * 32 + j * 8] = ((const u16x8*)src)[j];
    } else {
      u16x8 z = {};
#pragma unroll
      for (int j = 0; j < 4; ++j) *(u16x8*)&phs[r][q16 * 32 + j * 8] = z;
    }
    __syncthreads();

    // ---- phase C: wave (g, nh): 32 rows x 32 cols, K=512, weights in regs
    f32x4 acc[2][2] = {};
#pragma unroll
    for (int kb = 0; kb < 16; ++kb) {
      const int ko = kb * 32 + 8 * hi;
      bf16x8 a0 = *(const bf16x8*)&phs[l15][ko];
      bf16x8 a1 = *(const bf16x8*)&phs[16 + l15][ko];
      acc[0][0] = __builtin_amdgcn_mfma_f32_16x16x32_bf16(a0, wfrag[0][kb], acc[0][0], 0, 0, 0);
      acc[1][0] = __builtin_amdgcn_mfma_f32_16x16x32_bf16(a1, wfrag[0][kb], acc[1][0], 0, 0, 0);
      acc[0][1] = __builtin_amdgcn_mfma_f32_16x16x32_bf16(a0, wfrag[1][kb], acc[0][1], 0, 0, 0);
      acc[1][1] = __builtin_amdgcn_mfma_f32_16x16x32_bf16(a1, wfrag[1][kb], acc[1][1], 0, 0, 0);
    }
#pragma unroll
    for (int mi = 0; mi < 2; ++mi)
#pragma unroll
      for (int ni = 0; ni < 2; ++ni)
#pragma unroll
        for (int qq = 0; qq < 4; ++qq)
          gbuf[g][mi * 16 + hi * 4 + qq][nh * 32 + ni * 16 + l15] = acc[mi][ni][qq];
    __syncthreads();

    // ---- phase D: elementwise gates; prefetched xga/pc consumed here ----
    if (r < rcnt) {
      const int t = node >> 7;
      float xg[4][4];
#pragma unroll
      for (int gg = 0; gg < 4; ++gg)
#pragma unroll
        for (int j = 0; j < 4; ++j) xg[gg][j] = bf2f(xga[gg][j]);
      const float pcv[4] = {pc.x, pc.y, pc.z, pc.w};
      float cva[4], hva[4];
#pragma unroll
      for (int j = 0; j < 4; ++j) {
        float iv = sigm(gbuf[0][r][hc + j] + xg[0][j]);
        float fv = sigm(gbuf[1][r][hc + j] + xg[1][j]);
        float ov = sigm(gbuf[2][r][hc + j] + xg[2][j]);
        float uv = tanh_f(gbuf[3][r][hc + j] + xg[3][j]);
        float cv = iv * uv + fv * pcv[j];
        cva[j] = cv;
        hva[j] = ov * tanh_f(cv);
      }
      const size_t obase = ((size_t)b * LL + t) * HHH + h;
      *(float4*)(Hout + obase) = make_float4(hva[0], hva[1], hva[2], hva[3]);
      union { float f[4]; unsigned long long u[2]; } cvu;
      cvu.f[0] = cva[0]; cvu.f[1] = cva[1]; cvu.f[2] = cva[2]; cvu.f[3] = cva[3];
      unsigned long long* cp = (unsigned long long*)(Cbuf + obase);
      __hip_atomic_store(cp, cvu.u[0], __ATOMIC_RELAXED, __HIP_MEMORY_SCOPE_AGENT);
      __hip_atomic_store(cp + 1, cvu.u[1], __ATOMIC_RELAXED, __HIP_MEMORY_SCOPE_AGENT);
      union { unsigned short s[4]; unsigned long long u; } hbu;
      hbu.s[0] = f2bf(hva[0]); hbu.s[1] = f2bf(hva[1]);
      hbu.s[2] = f2bf(hva[2]); hbu.s[3] = f2bf(hva[3]);
      __hip_atomic_store((unsigned long long*)(Hbf + obase), hbu.u,
                         __ATOMIC_RELAXED, __HIP_MEMORY_SCOPE_AGENT);
    }
    // drain this wave's LLC stores (all 16 threads of each row are in-wave)
    asm volatile("s_waitcnt vmcnt(0)" ::: "memory");
    if (r < rcnt && q16 == 0)
      __hip_atomic_fetch_add(&flag[node], 1, __ATOMIC_RELAXED,
                             __HIP_MEMORY_SCOPE_AGENT);
  }
}

// ---------------------------------------------------------------------------
extern "C" void kernel_launch(void* const* d_in, const int* in_sizes, int n_in,
                              void* d_out, int out_size, void* d_ws, size_t ws_size,
                              hipStream_t stream) {
  const float* X    = (const float*)d_in[0];
  const float* Wi_x = (const float*)d_in[1];
  const float* bi_x = (const float*)d_in[2];
  const float* Wi_h = (const float*)d_in[3];
  const float* bi_h = (const float*)d_in[4];
  const float* Wf_x = (const float*)d_in[5];
  const float* bf_x = (const float*)d_in[6];
  const float* Wf_h = (const float*)d_in[7];
  const float* bf_h = (const float*)d_in[8];
  const float* Wo_x = (const float*)d_in[9];
  const float* Wo_h = (const float*)d_in[10];
  const float* Wu_x = (const float*)d_in[11];
  const float* Wu_h = (const float*)d_in[12];
  const int* parents = (const int*)d_in[13];
  float* Hout = (float*)d_out;

  char* ws = (char*)d_ws;
  unsigned short* Xpre = (unsigned short*)ws; ws += (size_t)32768 * 2048 * 2;  // 128 MB
  unsigned short* Hbf  = (unsigned short*)ws; ws += (size_t)BB * LL * HHH * 2; // 32 MB
  float*          Cbuf = (float*)ws;          ws += (size_t)BB * LL * HHH * 4; // 64 MB
  unsigned short* Wxbf = (unsigned short*)ws; ws += (size_t)2048 * 512 * 2;    // 2 MB
  unsigned short* Whp  = (unsigned short*)ws; ws += (size_t)2048 * 512 * 2;    // 2 MB
  int*            pairs = (int*)ws;           ws += (size_t)32768 * 4;         // 128 KB
  int*            lmeta = (int*)ws;           ws += 256 * 4;
  int*            mrows = (int*)ws;           ws += 4096 * 4;
  int*            flag  = (int*)ws;           ws += (size_t)32768 * 4;         // 128 KB
  int*            tick  = (int*)ws;           ws += 64 * 4;
  // Xbf ALIASES Cbuf: Xbf is dead after xproj2 completes; Cbuf is first
  // written inside treelstm_flag (stream-ordered after xproj2), and root
  // nodes never read Cbuf before a write.  Keeps total ws at round-5's
  // proven 239.4 MB (round 6's separate +32MB Xbf overflowed ws -> fault).
  unsigned short* Xbf = (unsigned short*)Cbuf;

  zero_flags<<<128, 256, 0, stream>>>(flag, tick);
  wcast4<<<1024, 256, 0, stream>>>(Wi_x, Wf_x, Wo_x, Wu_x, Wxbf);
  xcast<<<8192, 256, 0, stream>>>(X, Xbf);
  whpack<<<512, 256, 0, stream>>>(Wi_h, Wf_h, Wo_h, Wu_h, Whp);
  levels_k<<<1, 128, 0, stream>>>(parents, pairs, lmeta, mrows);
  dim3 g1(256, 16);
  xproj2<<<g1, 256, 0, stream>>>(Xbf, Wxbf, bi_x, bi_h, bf_x, bf_h, Xpre);

  treelstm_flag<<<512, 512, 0, stream>>>(Xpre, Whp, parents, pairs, lmeta,
                                         mrows, flag, tick, Hout, Cbuf, Hbf);
}